// Round 3
// baseline (1572.466 us; speedup 1.0000x reference)
//
#include <hip/hip_runtime.h>
#include <cstdint>
#include <cstddef>

typedef unsigned short u16;
typedef unsigned int u32;

typedef __bf16 bf16x8 __attribute__((ext_vector_type(8)));
typedef float f32x4 __attribute__((ext_vector_type(4)));
typedef unsigned short u16x8 __attribute__((ext_vector_type(8)));

__device__ __forceinline__ float bf2f(u16 v) { return __builtin_bit_cast(float, (u32)v << 16); }
__device__ __forceinline__ u16 f2bf(float f) {
    u32 u = __builtin_bit_cast(u32, f);
    u += 0x7fffu + ((u >> 16) & 1u);   // RNE
    return (u16)(u >> 16);
}
__device__ __forceinline__ bf16x8 ld8(const u16* p) {
    return __builtin_bit_cast(bf16x8, *(const uint4*)p);
}
__device__ __forceinline__ void glds16(const u16* g, u16* l) {
    __builtin_amdgcn_global_load_lds((const __attribute__((address_space(1))) void*)g,
                                     (__attribute__((address_space(3))) void*)l, 16, 0, 0);
}

// Bias selector: up to 4 pointer segments of 1024 floats each, indexed by n>>10.
struct B4 { const float* p[4]; };

// ---------------------------------------------------------------------------
// float32 -> bf16 elementwise convert (x -> Hb). n/1024 blocks of 256.
// ---------------------------------------------------------------------------
__global__ __launch_bounds__(256) void conv_f2b(const float* __restrict__ src,
                                                u16* __restrict__ dst)
{
    int idx = blockIdx.x * 256 + threadIdx.x;
    float4 v = ((const float4*)src)[idx];
    uint2 o;
    o.x = (u32)f2bf(v.x) | ((u32)f2bf(v.y) << 16);
    o.y = (u32)f2bf(v.z) | ((u32)f2bf(v.w) << 16);
    ((uint2*)dst)[idx] = o;
}

// ---------------------------------------------------------------------------
// GEMM: C = act( A[M,K] @ B[K,N] + bias[n] (+ R) ), A row-major bf16, B given
// TRANSPOSED bf16 (Bt element (n,k) at (n>>6)*nbs + (n&63)*ldb + k), bias via
// B4 segments (p[n>>10][n&1023], f32).
// C/R address: (m&1023)*crow + (m>>10)*cbatch + (n>>6)*chead + (n&63).
// M = gridDim.y*BM, N = gridDim.x*BN exactly; K multiple of 32.
// m97 structure: global_load_lds(16B) staging, 16x16x32 bf16 MFMA.
// ---------------------------------------------------------------------------
template <int BM, int BN>
__global__ __launch_bounds__(256) void gemm_bt(
    const u16* __restrict__ A, int lda,
    const u16* __restrict__ Bt, int ldb, int nbs,
    B4 bias,
    const u16* __restrict__ Rres,
    u16* __restrict__ C, int crow, int cbatch, int chead,
    int K, int relu)
{
    constexpr int WM = BM / 2, WN = BN / 2, FM = WM / 16, FN = WN / 16;
    __shared__ __align__(16) u16 Ald[BM * 32];
    __shared__ __align__(16) u16 Bld[BN * 32];
    const int tid = threadIdx.x;
    const int w = tid >> 6, lane = tid & 63;
    const int qd = lane >> 4, r = lane & 15;
    const int wr = w >> 1, wc = w & 1;
    const int m0 = blockIdx.y * BM, n0 = blockIdx.x * BN;
    const int arow = lane >> 2;          // staging: row within 16-row chunk
    const int acol = (lane & 3) * 8;     // staging: elem offset (16B lanes)

    f32x4 acc[FM][FN] = {};

    for (int k0 = 0; k0 < K; k0 += 32) {
#pragma unroll
        for (int ii = 0; ii < BM / 64; ++ii) {
            int rbase = w * (BM / 4) + ii * 16;
            glds16(A + (long)(m0 + rbase + arow) * lda + k0 + acol, &Ald[rbase * 32]);
        }
#pragma unroll
        for (int ii = 0; ii < BN / 64; ++ii) {
            int nbase = w * (BN / 4) + ii * 16;
            int ng = n0 + nbase + arow;
            glds16(Bt + (long)(ng >> 6) * nbs + (long)(ng & 63) * ldb + k0 + acol,
                   &Bld[nbase * 32]);
        }
        __syncthreads();   // drains vmcnt (glds) per barrier semantics
        bf16x8 af[FM], bb[FN];
#pragma unroll
        for (int fm = 0; fm < FM; ++fm)
            af[fm] = ld8(&Ald[(wr * WM + fm * 16 + r) * 32 + qd * 8]);
#pragma unroll
        for (int fn = 0; fn < FN; ++fn)
            bb[fn] = ld8(&Bld[(wc * WN + fn * 16 + r) * 32 + qd * 8]);
#pragma unroll
        for (int fm = 0; fm < FM; ++fm)
#pragma unroll
            for (int fn = 0; fn < FN; ++fn)
                acc[fm][fn] = __builtin_amdgcn_mfma_f32_16x16x32_bf16(af[fm], bb[fn],
                                                                      acc[fm][fn], 0, 0, 0);
        __syncthreads();
    }

#pragma unroll
    for (int fm = 0; fm < FM; ++fm) {
#pragma unroll
        for (int fn = 0; fn < FN; ++fn) {
            int ng = n0 + wc * WN + fn * 16 + r;
            float bs = bias.p[ng >> 10][ng & 1023];
            int naddr = (ng >> 6) * chead + (ng & 63);
#pragma unroll
            for (int j = 0; j < 4; ++j) {
                int mg = m0 + wr * WM + fm * 16 + qd * 4 + j;   // C/D row = quad*4+reg
                int caddr = (mg & 1023) * crow + (mg >> 10) * cbatch + naddr;
                float v = acc[fm][fn][j] + bs;
                if (Rres) v += bf2f(Rres[caddr]);
                if (relu) v = fmaxf(v, 0.f);
                C[caddr] = f2bf(v);
            }
        }
    }
}

// ---------------------------------------------------------------------------
// V transpose: per (h,b) pair, (s,dk) 1024x64 -> (dk,s) 64x1024.
// src/dst base offset = hb*65536 (hb = h*2+b). grid (32 s-tiles, 32 hb).
// ---------------------------------------------------------------------------
__global__ __launch_bounds__(256) void vtrans(const u16* __restrict__ src,
                                              u16* __restrict__ dst)
{
    __shared__ u16 tl[32][68];   // stride 68 u16 = 34 dwords -> 2-way bank alias (free)
    const long boff = (long)blockIdx.y * 65536;
    const int s0 = blockIdx.x * 32;
    const int c = threadIdx.x & 63, r4 = threadIdx.x >> 6;
#pragma unroll
    for (int i = 0; i < 8; ++i)
        tl[r4 + 4 * i][c] = src[boff + (long)(s0 + r4 + 4 * i) * 64 + c];
    __syncthreads();
    const int cs = threadIdx.x & 31, rs = threadIdx.x >> 5;
#pragma unroll
    for (int i = 0; i < 8; ++i)
        dst[boff + (long)(rs + 8 * i) * 1024 + s0 + cs] = tl[cs][rs + 8 * i];
}

// ---------------------------------------------------------------------------
// Fused attention: one block = (b,h) x 16 query rows.
// Q,K: (h,b,s,dk) bf16 at base h*131072 + b*65536. V: TRANSPOSED (h,b,dk,s).
// Max-free softmax (scores are small; clamp at 60 guards overflow; softmax is
// shift-invariant so skipping the max pass is exact): p = exp(min(s,60)) is
// written UNNORMALIZED to P (bf16) immediately per tile — no 64-reg live
// score array, no max-reduce chains, one barrier total. Row-sum is reduced
// per-wave then combined via LDS; normalization (1/sum) is folded into the
// PV output. maskp: keys >= *maskp get p = 0.
// ---------------------------------------------------------------------------
__global__ __launch_bounds__(256) void attn_kernel(
    const u16* __restrict__ Q, const u16* __restrict__ K,
    const u16* __restrict__ V, u16* __restrict__ O,
    const int* __restrict__ maskp)
{
    constexpr int PST = 1032;   // padded row stride (bf16 elems), 16B-aligned
    __shared__ __align__(16) u16 P[16 * PST];
    __shared__ float ssm[4][16];   // per-wave row sum of exp(s)
    const int tid = threadIdx.x;
    const int w = tid >> 6, lane = tid & 63;
    const int qd = lane >> 4, r = lane & 15;
    const int qt = blockIdx.x, bh = blockIdx.y;
    const int b = bh >> 4, h = bh & 15;
    const long base = (long)h * 131072 + (long)b * 65536;

    int mi = maskp ? *maskp : 1024;
    mi = mi < 0 ? 0 : (mi > 1024 ? 1024 : mi);
    const int nt = (mi + 15) >> 4;               // 16-wide key tiles to compute
    const int KC = nt ? ((nt * 16 + 31) & ~31) : 0;   // PV K extent (32-aligned)

    // Zero only the gap columns [nt*16, KC) (phase-1 covers cols < nt*16;
    // masked cols inside the last tile get exact 0 written directly).
    // Ordered before phase-3 reads by the single barrier below.
    if (KC > nt * 16) {
        int row = tid >> 4, col = nt * 16 + (tid & 15);
        P[row * PST + col] = 0;
    }

    // Q fragments (A operand: m=lane&15, k=quad*8+j)
    bf16x8 aq0 = ld8(&Q[base + (qt * 16 + r) * 64 + qd * 8]);
    bf16x8 aq1 = ld8(&Q[base + (qt * 16 + r) * 64 + 32 + qd * 8]);

    // Phase 1: scores -> p = exp(min(s,60)) -> P (unnormalized), sum per row.
    float sm[4] = {0.f, 0.f, 0.f, 0.f};
#pragma unroll
    for (int it = 0; it < 16; ++it) {
        int t = w + it * 4;
        if (t < nt) {
            const u16* kb = &K[base + (t * 16 + r) * 64 + qd * 8];
            f32x4 acc = {};
            acc = __builtin_amdgcn_mfma_f32_16x16x32_bf16(aq0, ld8(kb), acc, 0, 0, 0);
            acc = __builtin_amdgcn_mfma_f32_16x16x32_bf16(aq1, ld8(kb + 32), acc, 0, 0, 0);
            int col = t * 16 + r;
            bool valid = (col < mi);
#pragma unroll
            for (int j = 0; j < 4; ++j) {
                float p = valid ? __expf(fminf(acc[j] * 0.125f, 60.f)) : 0.f;
                sm[j] += p;
                P[(qd * 4 + j) * PST + col] = f2bf(p);
            }
        }
    }

    // Per-wave row-sum reduce over the 16 r-lanes (rows = qd*4+j).
#pragma unroll
    for (int d = 1; d < 16; d <<= 1)
#pragma unroll
        for (int j = 0; j < 4; ++j) sm[j] += __shfl_xor(sm[j], d);
    if (r == 0) {
#pragma unroll
        for (int j = 0; j < 4; ++j) ssm[w][qd * 4 + j] = sm[j];
    }
    __syncthreads();   // publishes P rows + ssm for all waves

    // Combine across waves: gs = sum_w sm_w; normalization folded into output.
    float scale[4];
#pragma unroll
    for (int j = 0; j < 4; ++j) {
        int row = qd * 4 + j;
        float gs = ssm[0][row] + ssm[1][row] + ssm[2][row] + ssm[3][row];
        scale[j] = 1.f / fmaxf(gs, 1e-30f);
    }

    // Phase 3: O_tile(16 x 64) = P(16 x KC) @ V(KC x 64); wave w -> cols w*16..+16
    // V is transposed (dk,s): one contiguous 16B load per MFMA B-fragment.
    f32x4 o = {};
    const u16* vb = &V[base + (long)(w * 16 + r) * 1024];
    for (int kk = 0; kk < KC; kk += 32) {
        bf16x8 pa = ld8(&P[r * PST + kk + qd * 8]);
        bf16x8 vv = ld8(&vb[kk + qd * 8]);
        o = __builtin_amdgcn_mfma_f32_16x16x32_bf16(pa, vv, o, 0, 0, 0);
    }
#pragma unroll
    for (int j = 0; j < 4; ++j) {
        int s = qt * 16 + qd * 4 + j;
        O[(long)(b * 1024 + s) * 1024 + h * 64 + w * 16 + r] = f2bf(o[j] * scale[j]);
    }
}

// ---------------------------------------------------------------------------
// BatchNorm1d over (B,S,D) with channel = s (S==D): stats over (b,d), biased
// var, eps=1e-5. One block per channel s. X bf16; writes bf16 to Y, or
// float32 to Yf if Yf != null (final layer). g/be float32. In-place safe.
// ---------------------------------------------------------------------------
__global__ __launch_bounds__(256) void bn_kernel(
    const u16* __restrict__ X, u16* __restrict__ Y, float* __restrict__ Yf,
    const float* __restrict__ g, const float* __restrict__ be)
{
    __shared__ float red[8];
    const int s = blockIdx.x, tid = threadIdx.x;
    const long b0 = (long)s * 1024, b1 = (long)(1024 + s) * 1024;
    uint2 a0 = *(const uint2*)&X[b0 + tid * 4];
    uint2 a1 = *(const uint2*)&X[b1 + tid * 4];
    float xs[8];
    xs[0] = bf2f((u16)a0.x); xs[1] = bf2f((u16)(a0.x >> 16));
    xs[2] = bf2f((u16)a0.y); xs[3] = bf2f((u16)(a0.y >> 16));
    xs[4] = bf2f((u16)a1.x); xs[5] = bf2f((u16)(a1.x >> 16));
    xs[6] = bf2f((u16)a1.y); xs[7] = bf2f((u16)(a1.y >> 16));
    float s1 = 0.f, s2 = 0.f;
#pragma unroll
    for (int j = 0; j < 8; ++j) { s1 += xs[j]; s2 += xs[j] * xs[j]; }
    for (int o = 32; o; o >>= 1) { s1 += __shfl_down(s1, o); s2 += __shfl_down(s2, o); }
    if ((tid & 63) == 0) { red[(tid >> 6) * 2] = s1; red[(tid >> 6) * 2 + 1] = s2; }
    __syncthreads();
    float S1 = red[0] + red[2] + red[4] + red[6];
    float S2 = red[1] + red[3] + red[5] + red[7];
    float mean = S1 * (1.f / 2048.f);
    float var = fmaxf(S2 * (1.f / 2048.f) - mean * mean, 0.f);
    float gs = g[s] * rsqrtf(var + 1e-5f);
    float bs = be[s];
    float y[8];
#pragma unroll
    for (int j = 0; j < 8; ++j) y[j] = (xs[j] - mean) * gs + bs;
    if (Yf) {
        *(float4*)&Yf[b0 + tid * 4] = make_float4(y[0], y[1], y[2], y[3]);
        *(float4*)&Yf[b1 + tid * 4] = make_float4(y[4], y[5], y[6], y[7]);
    } else {
        *(uint2*)&Y[b0 + tid * 4] = make_uint2(
            (u32)f2bf(y[0]) | ((u32)f2bf(y[1]) << 16),
            (u32)f2bf(y[2]) | ((u32)f2bf(y[3]) << 16));
        *(uint2*)&Y[b1 + tid * 4] = make_uint2(
            (u32)f2bf(y[4]) | ((u32)f2bf(y[5]) << 16),
            (u32)f2bf(y[6]) | ((u32)f2bf(y[7]) << 16));
    }
}

// ---------------------------------------------------------------------------
// One launch converts (f32 -> bf16) + transposes all 10 weight matrices of a
// layer into ws. s[0..5]: (16 heads)x(1024x64) QKV; s[6..7]: 1024x1024 Wo;
// s[8]: 1024x4096 W1; s[9]: 4096x1024 W2. 16384 blocks of 32x32 tiles.
// ---------------------------------------------------------------------------
struct TA { const float* s[10]; u16* d[10]; };

__global__ __launch_bounds__(256) void transpose_all(TA ta)
{
    __shared__ u16 tl[32][33];
    int id = blockIdx.x;
    const float* src; u16* dst; int Rr, Cc, tr, tc;
    if (id < 6144) {
        int wgt = id >> 10, rest = id & 1023;
        int head = rest >> 6, tile = rest & 63;
        tr = tile >> 1; tc = tile & 1; Rr = 1024; Cc = 64;
        src = ta.s[wgt] + head * 65536; dst = ta.d[wgt] + head * 65536;
    } else if (id < 8192) {
        int wgt = 6 + ((id - 6144) >> 10), rest = (id - 6144) & 1023;
        tr = rest >> 5; tc = rest & 31; Rr = 1024; Cc = 1024;
        src = ta.s[wgt]; dst = ta.d[wgt];
    } else if (id < 12288) {
        int rest = id - 8192;
        tr = rest >> 7; tc = rest & 127; Rr = 1024; Cc = 4096;
        src = ta.s[8]; dst = ta.d[8];
    } else {
        int rest = id - 12288;
        tr = rest >> 5; tc = rest & 31; Rr = 4096; Cc = 1024;
        src = ta.s[9]; dst = ta.d[9];
    }
    int r0 = tr * 32, c0 = tc * 32;
    int cl = threadIdx.x & 31, rl = threadIdx.x >> 5;
#pragma unroll
    for (int i = 0; i < 4; ++i)
        tl[rl + 8 * i][cl] = f2bf(src[(long)(r0 + rl + 8 * i) * Cc + c0 + cl]);
    __syncthreads();
#pragma unroll
    for (int i = 0; i < 4; ++i)
        dst[(long)(c0 + rl + 8 * i) * Rr + r0 + cl] = tl[cl][rl + 8 * i];
}

// ---------------------------------------------------------------------------
extern "C" void kernel_launch(void* const* d_in, const int* in_sizes, int n_in,
                              void* d_out, int out_size, void* d_ws, size_t ws_size,
                              hipStream_t stream)
{
    (void)in_sizes; (void)n_in; (void)out_size;
    const float* x   = (const float*)d_in[0];
    const float* Wq1 = (const float*)d_in[1];
    const float* bq1 = (const float*)d_in[2];
    const float* Wk1 = (const float*)d_in[3];
    const float* bk1 = (const float*)d_in[4];
    const float* Wv1 = (const float*)d_in[5];
    const float* bv1 = (const float*)d_in[6];
    const float* Wo1 = (const float*)d_in[7];
    const float* bo1 = (const float*)d_in[8];
    const float* Wq2 = (const float*)d_in[9];
    const float* bq2 = (const float*)d_in[10];
    const float* Wk2 = (const float*)d_in[11];
    const float* bk2 = (const float*)d_in[12];
    const float* Wv2 = (const float*)d_in[13];
    const float* bv2 = (const float*)d_in[14];
    const float* Wo2 = (const float*)d_in[15];
    const float* bo2 = (const float*)d_in[16];
    const float* g1  = (const float*)d_in[17];
    const float* be1 = (const float*)d_in[18];
    const float* g2  = (const float*)d_in[19];
    const float* be2 = (const float*)d_in[20];
    const float* g3  = (const float*)d_in[21];
    const float* be3 = (const float*)d_in[22];
    const float* W1  = (const float*)d_in[23];
    const float* bf1 = (const float*)d_in[24];
    const float* W2  = (const float*)d_in[25];
    const float* bf2 = (const float*)d_in[26];
    const int* maskp = (const int*)d_in[27];

    u16* ws = (u16*)d_ws;
    const size_t M1 = 1u << 20;
    u16* WT  = ws;             // 16M elems: transposed bf16 weights of current layer
    u16* QKV = ws + 16 * M1;   // 6M: fused QKV out, layout (h'=0..47, b, s, dk)
    u16* Vt  = ws + 22 * M1;   // 2M: V transposed (h, b, dk, s)
    u16* Ab  = ws + 24 * M1;   // 2M: attn out; reused as T2 in FFN
    u16* X1  = ws + 26 * M1;
    u16* Yb  = ws + 28 * M1;
    u16* Hb  = ws + 30 * M1;   // bf16 hidden state (layer input)
    u16* HID = ws + 32 * M1;   // 8M elems
    u16* T2  = Ab;             // FFN2 output (Ab dead by then)
    if (ws_size < (size_t)(40 * M1) * sizeof(u16)) return;  // fail loud (poisoned out)

    dim3 blk(256);
    dim3 g64(16, 32);     // 64x64 tiles (unused now but kept for reference)
    dim3 g128(32, 16);    // FFN1: 128x128 tiles
    dim3 gqkv(48, 16);    // fused QKV: N=3072, 128x64 tiles (768 blocks)
    dim3 g12864(16, 16);  // O-proj / FFN2: 128x64 tiles (256 blocks)
    dim3 gvt(32, 32);     // vtrans
    (void)g64;

    // x (f32) -> Hb (bf16)
    conv_f2b<<<dim3(2048), blk, 0, stream>>>(x, Hb);

    for (int l = 0; l < 4; ++l) {
        const u16* hin = Hb;

        TA ta;
        ta.s[0] = Wq1 + (size_t)l * M1;     ta.d[0] = WT + 0 * M1;
        ta.s[1] = Wk1 + (size_t)l * M1;     ta.d[1] = WT + 1 * M1;
        ta.s[2] = Wv1 + (size_t)l * M1;     ta.d[2] = WT + 2 * M1;
        ta.s[3] = Wq2 + (size_t)l * M1;     ta.d[3] = WT + 3 * M1;
        ta.s[4] = Wk2 + (size_t)l * M1;     ta.d[4] = WT + 4 * M1;
        ta.s[5] = Wv2 + (size_t)l * M1;     ta.d[5] = WT + 5 * M1;
        ta.s[6] = Wo1 + (size_t)l * M1;     ta.d[6] = WT + 6 * M1;
        ta.s[7] = Wo2 + (size_t)l * M1;     ta.d[7] = WT + 7 * M1;
        ta.s[8] = W1  + (size_t)l * 4 * M1; ta.d[8] = WT + 8 * M1;
        ta.s[9] = W2  + (size_t)l * 4 * M1; ta.d[9] = WT + 12 * M1;
        transpose_all<<<dim3(16384), blk, 0, stream>>>(ta);

        // ---- MHA1 (masked) ----
        B4 bQKV1 = {{bq1 + l * 1024, bk1 + l * 1024, bv1 + l * 1024, nullptr}};
        gemm_bt<128, 64><<<gqkv, blk, 0, stream>>>(hin, 1024, WT + 0 * M1, 1024, 65536,
            bQKV1, nullptr, QKV, 64, 65536, 131072, 1024, 0);
        vtrans<<<gvt, blk, 0, stream>>>(QKV + 4 * M1, Vt);
        attn_kernel<<<dim3(64, 32), blk, 0, stream>>>(QKV, QKV + 2 * M1, Vt, Ab, maskp);
        B4 bO1 = {{bo1 + l * 1024, nullptr, nullptr, nullptr}};
        gemm_bt<128, 64><<<g12864, blk, 0, stream>>>(Ab, 1024, WT + 6 * M1, 1024, 65536,
            bO1, hin, X1, 1024, 1048576, 64, 1024, 0);
        bn_kernel<<<dim3(1024), blk, 0, stream>>>(X1, X1, nullptr, g1 + l * 1024, be1 + l * 1024);

        // ---- MHA2 (unmasked, input x1, residual h) ----
        B4 bQKV2 = {{bq2 + l * 1024, bk2 + l * 1024, bv2 + l * 1024, nullptr}};
        gemm_bt<128, 64><<<gqkv, blk, 0, stream>>>(X1, 1024, WT + 3 * M1, 1024, 65536,
            bQKV2, nullptr, QKV, 64, 65536, 131072, 1024, 0);
        vtrans<<<gvt, blk, 0, stream>>>(QKV + 4 * M1, Vt);
        attn_kernel<<<dim3(64, 32), blk, 0, stream>>>(QKV, QKV + 2 * M1, Vt, Ab, nullptr);
        B4 bO2 = {{bo2 + l * 1024, nullptr, nullptr, nullptr}};
        gemm_bt<128, 64><<<g12864, blk, 0, stream>>>(Ab, 1024, WT + 7 * M1, 1024, 65536,
            bO2, hin, Yb, 1024, 1048576, 64, 1024, 0);
        bn_kernel<<<dim3(1024), blk, 0, stream>>>(Yb, Yb, nullptr, g2 + l * 1024, be2 + l * 1024);

        // ---- FFN (residual from x1) ----
        B4 bF1 = {{bf1 + l * 4096, bf1 + l * 4096 + 1024,
                   bf1 + l * 4096 + 2048, bf1 + l * 4096 + 3072}};
        gemm_bt<128, 128><<<g128, blk, 0, stream>>>(Yb, 1024, WT + 8 * M1, 1024, 65536,
            bF1, nullptr, HID, 4096, 4194304, 64, 1024, 1);
        B4 bF2 = {{bf2 + l * 1024, nullptr, nullptr, nullptr}};
        gemm_bt<128, 64><<<g12864, blk, 0, stream>>>(HID, 4096, WT + 12 * M1, 4096, 262144,
            bF2, X1, T2, 1024, 1048576, 64, 4096, 0);
        bn_kernel<<<dim3(1024), blk, 0, stream>>>(T2, Hb,
            (l == 3) ? (float*)d_out : nullptr, g3 + l * 1024, be3 + l * 1024);
    }
}

// Round 4
// 1345.685 us; speedup vs baseline: 1.1685x; 1.1685x over previous
//
#include <hip/hip_runtime.h>
#include <cstdint>
#include <cstddef>

typedef unsigned short u16;
typedef unsigned int u32;

typedef __bf16 bf16x8 __attribute__((ext_vector_type(8)));
typedef float f32x4 __attribute__((ext_vector_type(4)));
typedef unsigned short u16x8 __attribute__((ext_vector_type(8)));

__device__ __forceinline__ float bf2f(u16 v) { return __builtin_bit_cast(float, (u32)v << 16); }
__device__ __forceinline__ u16 f2bf(float f) {
    u32 u = __builtin_bit_cast(u32, f);
    u += 0x7fffu + ((u >> 16) & 1u);   // RNE
    return (u16)(u >> 16);
}
__device__ __forceinline__ bf16x8 ld8(const u16* p) {
    return __builtin_bit_cast(bf16x8, *(const uint4*)p);
}
__device__ __forceinline__ void glds16(const u16* g, u16* l) {
    __builtin_amdgcn_global_load_lds((const __attribute__((address_space(1))) void*)g,
                                     (__attribute__((address_space(3))) void*)l, 16, 0, 0);
}

// Bias selector: up to 4 pointer segments of 1024 floats each, indexed by n>>10.
struct B4 { const float* p[4]; };

// ---------------------------------------------------------------------------
// float32 -> bf16 elementwise convert (x -> Hb). n/1024 blocks of 256.
// ---------------------------------------------------------------------------
__global__ __launch_bounds__(256) void conv_f2b(const float* __restrict__ src,
                                                u16* __restrict__ dst)
{
    int idx = blockIdx.x * 256 + threadIdx.x;
    float4 v = ((const float4*)src)[idx];
    uint2 o;
    o.x = (u32)f2bf(v.x) | ((u32)f2bf(v.y) << 16);
    o.y = (u32)f2bf(v.z) | ((u32)f2bf(v.w) << 16);
    ((uint2*)dst)[idx] = o;
}

// ---------------------------------------------------------------------------
// GEMM: C = act( A[M,K] @ B[K,N] + bias[n] (+ R) ), A row-major bf16, B given
// TRANSPOSED bf16 (Bt element (n,k) at (n>>6)*nbs + (n&63)*ldb + k), bias via
// B4 segments (p[n>>10][n&1023], f32).
// C/R address: (m&1023)*crow + (m>>10)*cbatch + (n>>6)*chead + (n&63).
// M = gridDim.y*BM, N = gridDim.x*BN exactly; K multiple of 64.
//
// K-loop: BK=64, double-buffered LDS, prefetch-issue before compute (one
// barrier per K-tile; its vmcnt-drain lands after the compute phase, hiding
// the load latency). LDS layout XOR-swizzled (rule: linear glds dest +
// inverse-swizzled GLOBAL source col + swizzled ds_read addr):
//   staging lane l of a wave covers (row=l>>3, 16B-blk=l&7) holding global
//   col-blk (l&7)^(l>>3); fragment read of global blk X at row uses LDS blk
//   X^(row&7). 16 read lanes spread over 8 bank-groups = 2-way = free.
// ---------------------------------------------------------------------------
template <int BM, int BN>
__global__ __launch_bounds__(256) void gemm_bt(
    const u16* __restrict__ A, int lda,
    const u16* __restrict__ Bt, int ldb, int nbs,
    B4 bias,
    const u16* __restrict__ Rres,
    u16* __restrict__ C, int crow, int cbatch, int chead,
    int K, int relu)
{
    constexpr int WM = BM / 2, WN = BN / 2, FM = WM / 16, FN = WN / 16;
    __shared__ __align__(16) u16 Ald[2][BM * 64];
    __shared__ __align__(16) u16 Bld[2][BN * 64];
    const int tid = threadIdx.x;
    const int w = tid >> 6, lane = tid & 63;
    const int qd = lane >> 4, r = lane & 15;
    const int wr = w >> 1, wc = w & 1;
    const int m0 = blockIdx.y * BM, n0 = blockIdx.x * BN;
    // staging: one glds16 per wave covers 8 rows x 64 cols (16B per lane)
    const int srow = lane >> 3;                        // row within 8-row stripe
    const int scol = ((lane ^ (lane >> 3)) & 7) * 8;   // inverse-swizzled src col

    auto stage = [&](int buf, int k0) {
#pragma unroll
        for (int ii = 0; ii < BM / 32; ++ii) {
            int rbase = w * (BM / 4) + ii * 8;
            glds16(A + (long)(m0 + rbase + srow) * lda + k0 + scol,
                   &Ald[buf][rbase * 64]);
        }
#pragma unroll
        for (int ii = 0; ii < BN / 32; ++ii) {
            int nbase = w * (BN / 4) + ii * 8;
            int ng = n0 + nbase + srow;
            glds16(Bt + (long)(ng >> 6) * nbs + (long)(ng & 63) * ldb + k0 + scol,
                   &Bld[buf][nbase * 64]);
        }
    };

    f32x4 acc[FM][FN] = {};
    const int nt = K >> 6;

    stage(0, 0);
    __syncthreads();   // drains prologue stage (vmcnt) per barrier semantics

    for (int t = 0; t < nt; ++t) {
        const int cur = t & 1;
        if (t + 1 < nt) stage(cur ^ 1, (t + 1) << 6);   // prefetch next tile
#pragma unroll
        for (int s = 0; s < 2; ++s) {
            bf16x8 af[FM], bb[FN];
#pragma unroll
            for (int fm = 0; fm < FM; ++fm) {
                int row = wr * WM + fm * 16 + r;
                int blk = ((s << 2) | qd) ^ (r & 7);
                af[fm] = ld8(&Ald[cur][row * 64 + blk * 8]);
            }
#pragma unroll
            for (int fn = 0; fn < FN; ++fn) {
                int row = wc * WN + fn * 16 + r;
                int blk = ((s << 2) | qd) ^ (r & 7);
                bb[fn] = ld8(&Bld[cur][row * 64 + blk * 8]);
            }
#pragma unroll
            for (int fm = 0; fm < FM; ++fm)
#pragma unroll
                for (int fn = 0; fn < FN; ++fn)
                    acc[fm][fn] = __builtin_amdgcn_mfma_f32_16x16x32_bf16(af[fm], bb[fn],
                                                                          acc[fm][fn], 0, 0, 0);
        }
        __syncthreads();   // all reads of buf[cur] done; prefetch drained
    }

#pragma unroll
    for (int fm = 0; fm < FM; ++fm) {
#pragma unroll
        for (int fn = 0; fn < FN; ++fn) {
            int ng = n0 + wc * WN + fn * 16 + r;
            float bs = bias.p[ng >> 10][ng & 1023];
            int naddr = (ng >> 6) * chead + (ng & 63);
#pragma unroll
            for (int j = 0; j < 4; ++j) {
                int mg = m0 + wr * WM + fm * 16 + qd * 4 + j;   // C/D row = quad*4+reg
                int caddr = (mg & 1023) * crow + (mg >> 10) * cbatch + naddr;
                float v = acc[fm][fn][j] + bs;
                if (Rres) v += bf2f(Rres[caddr]);
                if (relu) v = fmaxf(v, 0.f);
                C[caddr] = f2bf(v);
            }
        }
    }
}

// ---------------------------------------------------------------------------
// V transpose: per (h,b) pair, (s,dk) 1024x64 -> (dk,s) 64x1024.
// src/dst base offset = hb*65536 (hb = h*2+b). grid (32 s-tiles, 32 hb).
// ---------------------------------------------------------------------------
__global__ __launch_bounds__(256) void vtrans(const u16* __restrict__ src,
                                              u16* __restrict__ dst)
{
    __shared__ u16 tl[32][68];   // stride 68 u16 = 34 dwords -> 2-way bank alias (free)
    const long boff = (long)blockIdx.y * 65536;
    const int s0 = blockIdx.x * 32;
    const int c = threadIdx.x & 63, r4 = threadIdx.x >> 6;
#pragma unroll
    for (int i = 0; i < 8; ++i)
        tl[r4 + 4 * i][c] = src[boff + (long)(s0 + r4 + 4 * i) * 64 + c];
    __syncthreads();
    const int cs = threadIdx.x & 31, rs = threadIdx.x >> 5;
#pragma unroll
    for (int i = 0; i < 8; ++i)
        dst[boff + (long)(rs + 8 * i) * 1024 + s0 + cs] = tl[cs][rs + 8 * i];
}

// ---------------------------------------------------------------------------
// Fused attention: one block = (b,h) x 16 query rows.
// Q,K: (h,b,s,dk) bf16 at base h*131072 + b*65536. V: TRANSPOSED (h,b,dk,s).
// Max-free softmax (softmax is shift-invariant; clamp at 60 guards overflow):
// p = exp(min(s,60)) written UNNORMALIZED to P (bf16) immediately per tile;
// row-sum reduced per-wave then combined via LDS; normalization (1/sum)
// folded into the PV output. maskp: keys >= *maskp get p = 0.
// ---------------------------------------------------------------------------
__global__ __launch_bounds__(256) void attn_kernel(
    const u16* __restrict__ Q, const u16* __restrict__ K,
    const u16* __restrict__ V, u16* __restrict__ O,
    const int* __restrict__ maskp)
{
    constexpr int PST = 1032;   // padded row stride (bf16 elems), 16B-aligned
    __shared__ __align__(16) u16 P[16 * PST];
    __shared__ float ssm[4][16];   // per-wave row sum of exp(s)
    const int tid = threadIdx.x;
    const int w = tid >> 6, lane = tid & 63;
    const int qd = lane >> 4, r = lane & 15;
    const int qt = blockIdx.x, bh = blockIdx.y;
    const int b = bh >> 4, h = bh & 15;
    const long base = (long)h * 131072 + (long)b * 65536;

    int mi = maskp ? *maskp : 1024;
    mi = mi < 0 ? 0 : (mi > 1024 ? 1024 : mi);
    const int nt = (mi + 15) >> 4;               // 16-wide key tiles to compute
    const int KC = nt ? ((nt * 16 + 31) & ~31) : 0;   // PV K extent (32-aligned)

    // Zero only the gap columns [nt*16, KC) (phase-1 covers cols < nt*16;
    // masked cols inside the last tile get exact 0 written directly).
    if (KC > nt * 16) {
        int row = tid >> 4, col = nt * 16 + (tid & 15);
        P[row * PST + col] = 0;
    }

    // Q fragments (A operand: m=lane&15, k=quad*8+j)
    bf16x8 aq0 = ld8(&Q[base + (qt * 16 + r) * 64 + qd * 8]);
    bf16x8 aq1 = ld8(&Q[base + (qt * 16 + r) * 64 + 32 + qd * 8]);

    // Phase 1: scores -> p = exp(min(s,60)) -> P (unnormalized), sum per row.
    float sm[4] = {0.f, 0.f, 0.f, 0.f};
#pragma unroll
    for (int it = 0; it < 16; ++it) {
        int t = w + it * 4;
        if (t < nt) {
            const u16* kb = &K[base + (t * 16 + r) * 64 + qd * 8];
            f32x4 acc = {};
            acc = __builtin_amdgcn_mfma_f32_16x16x32_bf16(aq0, ld8(kb), acc, 0, 0, 0);
            acc = __builtin_amdgcn_mfma_f32_16x16x32_bf16(aq1, ld8(kb + 32), acc, 0, 0, 0);
            int col = t * 16 + r;
            bool valid = (col < mi);
#pragma unroll
            for (int j = 0; j < 4; ++j) {
                float p = valid ? __expf(fminf(acc[j] * 0.125f, 60.f)) : 0.f;
                sm[j] += p;
                P[(qd * 4 + j) * PST + col] = f2bf(p);
            }
        }
    }

    // Per-wave row-sum reduce over the 16 r-lanes (rows = qd*4+j).
#pragma unroll
    for (int d = 1; d < 16; d <<= 1)
#pragma unroll
        for (int j = 0; j < 4; ++j) sm[j] += __shfl_xor(sm[j], d);
    if (r == 0) {
#pragma unroll
        for (int j = 0; j < 4; ++j) ssm[w][qd * 4 + j] = sm[j];
    }
    __syncthreads();   // publishes P rows + ssm for all waves

    // Combine across waves: gs = sum_w sm_w; normalization folded into output.
    float scale[4];
#pragma unroll
    for (int j = 0; j < 4; ++j) {
        int row = qd * 4 + j;
        float gs = ssm[0][row] + ssm[1][row] + ssm[2][row] + ssm[3][row];
        scale[j] = 1.f / fmaxf(gs, 1e-30f);
    }

    // Phase 3: O_tile(16 x 64) = P(16 x KC) @ V(KC x 64); wave w -> cols w*16..+16
    // V is transposed (dk,s): one contiguous 16B load per MFMA B-fragment.
    f32x4 o = {};
    const u16* vb = &V[base + (long)(w * 16 + r) * 1024];
    for (int kk = 0; kk < KC; kk += 32) {
        bf16x8 pa = ld8(&P[r * PST + kk + qd * 8]);
        bf16x8 vv = ld8(&vb[kk + qd * 8]);
        o = __builtin_amdgcn_mfma_f32_16x16x32_bf16(pa, vv, o, 0, 0, 0);
    }
#pragma unroll
    for (int j = 0; j < 4; ++j) {
        int s = qt * 16 + qd * 4 + j;
        O[(long)(b * 1024 + s) * 1024 + h * 64 + w * 16 + r] = f2bf(o[j] * scale[j]);
    }
}

// ---------------------------------------------------------------------------
// BatchNorm1d over (B,S,D) with channel = s (S==D): stats over (b,d), biased
// var, eps=1e-5. One block per channel s. X bf16; writes bf16 to Y, or
// float32 to Yf if Yf != null (final layer). g/be float32. In-place safe.
// ---------------------------------------------------------------------------
__global__ __launch_bounds__(256) void bn_kernel(
    const u16* __restrict__ X, u16* __restrict__ Y, float* __restrict__ Yf,
    const float* __restrict__ g, const float* __restrict__ be)
{
    __shared__ float red[8];
    const int s = blockIdx.x, tid = threadIdx.x;
    const long b0 = (long)s * 1024, b1 = (long)(1024 + s) * 1024;
    uint2 a0 = *(const uint2*)&X[b0 + tid * 4];
    uint2 a1 = *(const uint2*)&X[b1 + tid * 4];
    float xs[8];
    xs[0] = bf2f((u16)a0.x); xs[1] = bf2f((u16)(a0.x >> 16));
    xs[2] = bf2f((u16)a0.y); xs[3] = bf2f((u16)(a0.y >> 16));
    xs[4] = bf2f((u16)a1.x); xs[5] = bf2f((u16)(a1.x >> 16));
    xs[6] = bf2f((u16)a1.y); xs[7] = bf2f((u16)(a1.y >> 16));
    float s1 = 0.f, s2 = 0.f;
#pragma unroll
    for (int j = 0; j < 8; ++j) { s1 += xs[j]; s2 += xs[j] * xs[j]; }
    for (int o = 32; o; o >>= 1) { s1 += __shfl_down(s1, o); s2 += __shfl_down(s2, o); }
    if ((tid & 63) == 0) { red[(tid >> 6) * 2] = s1; red[(tid >> 6) * 2 + 1] = s2; }
    __syncthreads();
    float S1 = red[0] + red[2] + red[4] + red[6];
    float S2 = red[1] + red[3] + red[5] + red[7];
    float mean = S1 * (1.f / 2048.f);
    float var = fmaxf(S2 * (1.f / 2048.f) - mean * mean, 0.f);
    float gs = g[s] * rsqrtf(var + 1e-5f);
    float bs = be[s];
    float y[8];
#pragma unroll
    for (int j = 0; j < 8; ++j) y[j] = (xs[j] - mean) * gs + bs;
    if (Yf) {
        *(float4*)&Yf[b0 + tid * 4] = make_float4(y[0], y[1], y[2], y[3]);
        *(float4*)&Yf[b1 + tid * 4] = make_float4(y[4], y[5], y[6], y[7]);
    } else {
        *(uint2*)&Y[b0 + tid * 4] = make_uint2(
            (u32)f2bf(y[0]) | ((u32)f2bf(y[1]) << 16),
            (u32)f2bf(y[2]) | ((u32)f2bf(y[3]) << 16));
        *(uint2*)&Y[b1 + tid * 4] = make_uint2(
            (u32)f2bf(y[4]) | ((u32)f2bf(y[5]) << 16),
            (u32)f2bf(y[6]) | ((u32)f2bf(y[7]) << 16));
    }
}

// ---------------------------------------------------------------------------
// One launch converts (f32 -> bf16) + transposes all 10 weight matrices of a
// layer into ws. s[0..5]: (16 heads)x(1024x64) QKV; s[6..7]: 1024x1024 Wo;
// s[8]: 1024x4096 W1; s[9]: 4096x1024 W2. 16384 blocks of 32x32 tiles.
// ---------------------------------------------------------------------------
struct TA { const float* s[10]; u16* d[10]; };

__global__ __launch_bounds__(256) void transpose_all(TA ta)
{
    __shared__ u16 tl[32][33];
    int id = blockIdx.x;
    const float* src; u16* dst; int Rr, Cc, tr, tc;
    if (id < 6144) {
        int wgt = id >> 10, rest = id & 1023;
        int head = rest >> 6, tile = rest & 63;
        tr = tile >> 1; tc = tile & 1; Rr = 1024; Cc = 64;
        src = ta.s[wgt] + head * 65536; dst = ta.d[wgt] + head * 65536;
    } else if (id < 8192) {
        int wgt = 6 + ((id - 6144) >> 10), rest = (id - 6144) & 1023;
        tr = rest >> 5; tc = rest & 31; Rr = 1024; Cc = 1024;
        src = ta.s[wgt]; dst = ta.d[wgt];
    } else if (id < 12288) {
        int rest = id - 8192;
        tr = rest >> 7; tc = rest & 127; Rr = 1024; Cc = 4096;
        src = ta.s[8]; dst = ta.d[8];
    } else {
        int rest = id - 12288;
        tr = rest >> 5; tc = rest & 31; Rr = 4096; Cc = 1024;
        src = ta.s[9]; dst = ta.d[9];
    }
    int r0 = tr * 32, c0 = tc * 32;
    int cl = threadIdx.x & 31, rl = threadIdx.x >> 5;
#pragma unroll
    for (int i = 0; i < 4; ++i)
        tl[rl + 8 * i][cl] = f2bf(src[(long)(r0 + rl + 8 * i) * Cc + c0 + cl]);
    __syncthreads();
#pragma unroll
    for (int i = 0; i < 4; ++i)
        dst[(long)(c0 + rl + 8 * i) * Rr + r0 + cl] = tl[cl][rl + 8 * i];
}

// ---------------------------------------------------------------------------
extern "C" void kernel_launch(void* const* d_in, const int* in_sizes, int n_in,
                              void* d_out, int out_size, void* d_ws, size_t ws_size,
                              hipStream_t stream)
{
    (void)in_sizes; (void)n_in; (void)out_size;
    const float* x   = (const float*)d_in[0];
    const float* Wq1 = (const float*)d_in[1];
    const float* bq1 = (const float*)d_in[2];
    const float* Wk1 = (const float*)d_in[3];
    const float* bk1 = (const float*)d_in[4];
    const float* Wv1 = (const float*)d_in[5];
    const float* bv1 = (const float*)d_in[6];
    const float* Wo1 = (const float*)d_in[7];
    const float* bo1 = (const float*)d_in[8];
    const float* Wq2 = (const float*)d_in[9];
    const float* bq2 = (const float*)d_in[10];
    const float* Wk2 = (const float*)d_in[11];
    const float* bk2 = (const float*)d_in[12];
    const float* Wv2 = (const float*)d_in[13];
    const float* bv2 = (const float*)d_in[14];
    const float* Wo2 = (const float*)d_in[15];
    const float* bo2 = (const float*)d_in[16];
    const float* g1  = (const float*)d_in[17];
    const float* be1 = (const float*)d_in[18];
    const float* g2  = (const float*)d_in[19];
    const float* be2 = (const float*)d_in[20];
    const float* g3  = (const float*)d_in[21];
    const float* be3 = (const float*)d_in[22];
    const float* W1  = (const float*)d_in[23];
    const float* bf1 = (const float*)d_in[24];
    const float* W2  = (const float*)d_in[25];
    const float* bf2 = (const float*)d_in[26];
    const int* maskp = (const int*)d_in[27];

    u16* ws = (u16*)d_ws;
    const size_t M1 = 1u << 20;
    u16* WT  = ws;             // 16M elems: transposed bf16 weights of current layer
    u16* QKV = ws + 16 * M1;   // 6M: fused QKV out, layout (h'=0..47, b, s, dk)
    u16* Vt  = ws + 22 * M1;   // 2M: V transposed (h, b, dk, s)
    u16* Ab  = ws + 24 * M1;   // 2M: attn out; reused as T2 in FFN
    u16* X1  = ws + 26 * M1;
    u16* Yb  = ws + 28 * M1;
    u16* Hb  = ws + 30 * M1;   // bf16 hidden state (layer input)
    u16* HID = ws + 32 * M1;   // 8M elems
    u16* T2  = Ab;             // FFN2 output (Ab dead by then)
    if (ws_size < (size_t)(40 * M1) * sizeof(u16)) return;  // fail loud (poisoned out)

    dim3 blk(256);
    dim3 g64(16, 32);     // O-proj / FFN2: 64x64 tiles, 512 blocks (2/CU)
    dim3 gqkv(48, 16);    // fused QKV: N=3072, 128x64 tiles (768 blocks, 3/CU)
    dim3 gF1(64, 16);     // FFN1: N=4096, 128x64 tiles (1024 blocks, 4/CU)
    dim3 gvt(32, 32);     // vtrans

    // x (f32) -> Hb (bf16)
    conv_f2b<<<dim3(2048), blk, 0, stream>>>(x, Hb);

    for (int l = 0; l < 4; ++l) {
        const u16* hin = Hb;

        TA ta;
        ta.s[0] = Wq1 + (size_t)l * M1;     ta.d[0] = WT + 0 * M1;
        ta.s[1] = Wk1 + (size_t)l * M1;     ta.d[1] = WT + 1 * M1;
        ta.s[2] = Wv1 + (size_t)l * M1;     ta.d[2] = WT + 2 * M1;
        ta.s[3] = Wq2 + (size_t)l * M1;     ta.d[3] = WT + 3 * M1;
        ta.s[4] = Wk2 + (size_t)l * M1;     ta.d[4] = WT + 4 * M1;
        ta.s[5] = Wv2 + (size_t)l * M1;     ta.d[5] = WT + 5 * M1;
        ta.s[6] = Wo1 + (size_t)l * M1;     ta.d[6] = WT + 6 * M1;
        ta.s[7] = Wo2 + (size_t)l * M1;     ta.d[7] = WT + 7 * M1;
        ta.s[8] = W1  + (size_t)l * 4 * M1; ta.d[8] = WT + 8 * M1;
        ta.s[9] = W2  + (size_t)l * 4 * M1; ta.d[9] = WT + 12 * M1;
        transpose_all<<<dim3(16384), blk, 0, stream>>>(ta);

        // ---- MHA1 (masked) ----
        B4 bQKV1 = {{bq1 + l * 1024, bk1 + l * 1024, bv1 + l * 1024, nullptr}};
        gemm_bt<128, 64><<<gqkv, blk, 0, stream>>>(hin, 1024, WT + 0 * M1, 1024, 65536,
            bQKV1, nullptr, QKV, 64, 65536, 131072, 1024, 0);
        vtrans<<<gvt, blk, 0, stream>>>(QKV + 4 * M1, Vt);
        attn_kernel<<<dim3(64, 32), blk, 0, stream>>>(QKV, QKV + 2 * M1, Vt, Ab, maskp);
        B4 bO1 = {{bo1 + l * 1024, nullptr, nullptr, nullptr}};
        gemm_bt<64, 64><<<g64, blk, 0, stream>>>(Ab, 1024, WT + 6 * M1, 1024, 65536,
            bO1, hin, X1, 1024, 1048576, 64, 1024, 0);
        bn_kernel<<<dim3(1024), blk, 0, stream>>>(X1, X1, nullptr, g1 + l * 1024, be1 + l * 1024);

        // ---- MHA2 (unmasked, input x1, residual h) ----
        B4 bQKV2 = {{bq2 + l * 1024, bk2 + l * 1024, bv2 + l * 1024, nullptr}};
        gemm_bt<128, 64><<<gqkv, blk, 0, stream>>>(X1, 1024, WT + 3 * M1, 1024, 65536,
            bQKV2, nullptr, QKV, 64, 65536, 131072, 1024, 0);
        vtrans<<<gvt, blk, 0, stream>>>(QKV + 4 * M1, Vt);
        attn_kernel<<<dim3(64, 32), blk, 0, stream>>>(QKV, QKV + 2 * M1, Vt, Ab, nullptr);
        B4 bO2 = {{bo2 + l * 1024, nullptr, nullptr, nullptr}};
        gemm_bt<64, 64><<<g64, blk, 0, stream>>>(Ab, 1024, WT + 7 * M1, 1024, 65536,
            bO2, hin, Yb, 1024, 1048576, 64, 1024, 0);
        bn_kernel<<<dim3(1024), blk, 0, stream>>>(Yb, Yb, nullptr, g2 + l * 1024, be2 + l * 1024);

        // ---- FFN (residual from x1) ----
        B4 bF1 = {{bf1 + l * 4096, bf1 + l * 4096 + 1024,
                   bf1 + l * 4096 + 2048, bf1 + l * 4096 + 3072}};
        gemm_bt<128, 64><<<gF1, blk, 0, stream>>>(Yb, 1024, WT + 8 * M1, 1024, 65536,
            bF1, nullptr, HID, 4096, 4194304, 64, 1024, 1);
        B4 bF2 = {{bf2 + l * 1024, nullptr, nullptr, nullptr}};
        gemm_bt<64, 64><<<g64, blk, 0, stream>>>(HID, 4096, WT + 12 * M1, 4096, 262144,
            bF2, X1, T2, 1024, 1048576, 64, 4096, 0);
        bn_kernel<<<dim3(1024), blk, 0, stream>>>(T2, Hb,
            (l == 3) ? (float*)d_out : nullptr, g3 + l * 1024, be3 + l * 1024);
    }
}